// Round 10
// baseline (213.439 us; speedup 1.0000x reference)
//
#include <hip/hip_runtime.h>

#define BN 32768
#define IN 512
#define NE 8
#define NH 128
#define MO 256

typedef const __attribute__((address_space(1))) unsigned int gu32;
typedef __attribute__((address_space(3))) unsigned int lu32;
typedef __attribute__((ext_vector_type(8))) short bf16x8;
typedef __attribute__((ext_vector_type(4))) float f32x4;

// async global->LDS, 16B per lane. LDS dest = wave-uniform base + lane*16.
__device__ __forceinline__ void cp16(const float* g, float* l) {
    __builtin_amdgcn_global_load_lds((gu32*)g, (lu32*)l, 16, 0, 0);
}

// f32 -> bf16 bits, round-to-nearest-even
__device__ __forceinline__ unsigned short f2bf(float f) {
    unsigned int u = __float_as_uint(f);
    u = (u + 0x7fffu + ((u >> 16) & 1u)) >> 16;
    return (unsigned short)u;
}
__device__ __forceinline__ float bf2f(unsigned short h) {
    return __uint_as_float((unsigned int)h << 16);
}

// ---------------- fused gate (blocks 0..511) + weight prep (512..607) -------
// Both paths byte-identical to R7/R8/R9 (verified passing).
__global__ __launch_bounds__(256) void gatep_kernel(
    const float* __restrict__ x, const float* __restrict__ wg,
    const float* __restrict__ W1, const float* __restrict__ W2,
    float* __restrict__ W1F, float* __restrict__ W2F,
    int* __restrict__ gcount, int* __restrict__ gload, float* __restrict__ gimp,
    int* __restrict__ idx_list, float* __restrict__ gate_list,
    float* __restrict__ out, const float* __restrict__ bout)
{
    __shared__ __align__(16) char wb[32768];
    __shared__ int counts_s[NE];
    __shared__ int load_s[NE];
    __shared__ float imp_s[NE];
    __shared__ int base_s[NE];
    __shared__ int rec_e[128];
    __shared__ int rec_p[128];
    __shared__ float rec_g[128];

    int tid = threadIdx.x;
    int bx = blockIdx.x;

    if (bx >= 512) {    // ---------- prep path ----------
        char* pb = wb;
        int t = tid, b = bx - 512;
        if (b < 64) {                       // W1: e = b>>3, ktile(64 k) = b&7
            int e = b >> 3, kt = b & 7;
            const float* src = W1 + ((size_t)e * IN + kt * 64) * NH;
            #pragma unroll
            for (int p = 0; p < 8; ++p) {
                int li = p * 256 + t;
                float4 q = *(const float4*)(src + li * 4);
                int kl = li >> 5, n0 = (li & 31) * 4;
                int ks = kl >> 5, g = (kl >> 3) & 3, kb = (kl & 7) * 2;
                float vv[4] = {q.x, q.y, q.z, q.w};
                #pragma unroll
                for (int j = 0; j < 4; ++j) {
                    int n = n0 + j;
                    int off = (((ks * 8 + (n >> 4)) * 64) + (n & 15) + 16 * g) * 16 + kb;
                    unsigned short hh = f2bf(vv[j]);
                    unsigned short hl = f2bf(vv[j] - bf2f(hh));
                    *(unsigned short*)(pb + off) = hh;
                    *(unsigned short*)(pb + 16384 + off) = hl;
                }
            }
            __syncthreads();
            float* dst = W1F + (size_t)b * 8192;
            #pragma unroll
            for (int p = 0; p < 8; ++p) {
                int li = p * 256 + t;
                *(int4*)(dst + li * 4) = *(const int4*)(pb + li * 16);
            }
        } else {                            // W2: e = bi>>2, ktile(32 k) = bi&3
            int bi = b - 64;
            int e = bi >> 2, kt = bi & 3;
            const float* src = W2 + ((size_t)e * NH + kt * 32) * MO;
            #pragma unroll
            for (int p = 0; p < 8; ++p) {
                int li = p * 256 + t;
                float4 q = *(const float4*)(src + li * 4);
                int kl = li >> 6, n0 = (li & 63) * 4;
                int g = kl >> 3, kb = (kl & 7) * 2;
                float vv[4] = {q.x, q.y, q.z, q.w};
                #pragma unroll
                for (int j = 0; j < 4; ++j) {
                    int n = n0 + j;
                    int off = ((n >> 4) * 64 + (n & 15) + 16 * g) * 16 + kb;
                    unsigned short hh = f2bf(vv[j]);
                    unsigned short hl = f2bf(vv[j] - bf2f(hh));
                    *(unsigned short*)(pb + off) = hh;
                    *(unsigned short*)(pb + 16384 + off) = hl;
                }
            }
            __syncthreads();
            float* dst = W2F + (size_t)bi * 8192;
            #pragma unroll
            for (int p = 0; p < 8; ++p) {
                int li = p * 256 + t;
                *(int4*)(dst + li * 4) = *(const int4*)(pb + li * 16);
            }
        }
        return;
    }

    // ---------- gate path ----------
    if (tid < NE) { counts_s[tid] = 0; load_s[tid] = 0; imp_s[tid] = 0.f; }
    if (tid < 128) {  // fused init: out[row, j] = bout[j]
        int row = bx * 64 + (tid >> 1);
        out[row * 2 + (tid & 1)] = bout[tid & 1];
    }
    for (int idx = tid; idx < 1024; idx += 256) {
        int ks = idx >> 6, ls = idx & 63;
        int col = ls & 15;
        int kb = 32 * ks + 8 * (ls >> 4);
        unsigned int ph[4], pl[4];
        #pragma unroll
        for (int j = 0; j < 4; ++j) {
            float v0 = (col < 8) ? wg[(kb + 2 * j) * NE + col] : 0.f;
            float v1 = (col < 8) ? wg[(kb + 2 * j + 1) * NE + col] : 0.f;
            unsigned short h0 = f2bf(v0), h1 = f2bf(v1);
            unsigned short l0 = f2bf(v0 - bf2f(h0)), l1 = f2bf(v1 - bf2f(h1));
            ph[j] = (unsigned int)h0 | ((unsigned int)h1 << 16);
            pl[j] = (unsigned int)l0 | ((unsigned int)l1 << 16);
        }
        *(int4*)(wb + ks * 1024 + ls * 16) = make_int4(ph[0], ph[1], ph[2], ph[3]);
        *(int4*)(wb + 16384 + ks * 1024 + ls * 16) = make_int4(pl[0], pl[1], pl[2], pl[3]);
    }
    __syncthreads();

    int w = tid >> 6, l = tid & 63;
    int e = l & 15;
    int rowA = bx * 64 + w * 16 + e;
    const float* px = x + (size_t)rowA * IN + 8 * (l >> 4);

    f32x4 acc = {};
    #pragma unroll
    for (int ks = 0; ks < 16; ++ks) {
        float4 qa = *(const float4*)(px + 32 * ks);
        float4 qb = *(const float4*)(px + 32 * ks + 4);
        float v[8] = {qa.x, qa.y, qa.z, qa.w, qb.x, qb.y, qb.z, qb.w};
        bf16x8 ah, al;
        #pragma unroll
        for (int i = 0; i < 8; ++i) {
            unsigned short h = f2bf(v[i]);
            ah[i] = (short)h;
            al[i] = (short)f2bf(v[i] - bf2f(h));
        }
        bf16x8 bh = *(const bf16x8*)(wb + ks * 1024 + l * 16);
        bf16x8 bl = *(const bf16x8*)(wb + 16384 + ks * 1024 + l * 16);
        acc = __builtin_amdgcn_mfma_f32_16x16x32_bf16(ah, bh, acc, 0, 0, 0);
        acc = __builtin_amdgcn_mfma_f32_16x16x32_bf16(ah, bl, acc, 0, 0, 0);
        acc = __builtin_amdgcn_mfma_f32_16x16x32_bf16(al, bh, acc, 0, 0, 0);
    }

    #pragma unroll
    for (int reg = 0; reg < 4; ++reg) {
        int rloc = w * 16 + 4 * (l >> 4) + reg;
        int row = bx * 64 + rloc;
        float lv = (e < 8) ? acc[reg] : -1e30f;

        float v0 = lv; int e0 = e;
        #pragma unroll
        for (int m = 1; m < 8; m <<= 1) {
            float vo = __shfl_xor(v0, m, 64);
            int eo = __shfl_xor(e0, m, 64);
            if (vo > v0 || (vo == v0 && eo < e0)) { v0 = vo; e0 = eo; }
        }
        float v1 = (e == e0 || e >= 8) ? -1e30f : lv; int e1 = e;
        #pragma unroll
        for (int m = 1; m < 8; m <<= 1) {
            float vo = __shfl_xor(v1, m, 64);
            int eo = __shfl_xor(e1, m, 64);
            if (vo > v1 || (vo == v1 && eo < e1)) { v1 = vo; e1 = eo; }
        }
        float v2 = (e == e0 || e == e1 || e >= 8) ? -1e30f : lv;
        #pragma unroll
        for (int m = 1; m < 8; m <<= 1) v2 = fmaxf(v2, __shfl_xor(v2, m, 64));

        double dv0 = v0, dv1 = v1;
        int f0 = e0, f1 = e1;
        if (e < 8 && v1 - v2 < 2e-4f) {   // rare exact recompute (group-uniform)
            const float* xr = x + (size_t)row * IN;
            double d0 = 0, d1 = 0, d2 = 0, d3 = 0;
            for (int k = 0; k < IN; k += 4) {
                float4 xv = *(const float4*)(xr + k);
                d0 = fma((double)xv.x, (double)wg[(k    ) * NE + e], d0);
                d1 = fma((double)xv.y, (double)wg[(k + 1) * NE + e], d1);
                d2 = fma((double)xv.z, (double)wg[(k + 2) * NE + e], d2);
                d3 = fma((double)xv.w, (double)wg[(k + 3) * NE + e], d3);
            }
            double ad = (d0 + d1) + (d2 + d3);
            double w0 = ad; int g0i = e;
            #pragma unroll
            for (int m = 1; m < 8; m <<= 1) {
                double vo = __shfl_xor(w0, m, 64);
                int eo = __shfl_xor(g0i, m, 64);
                if (vo > w0 || (vo == w0 && eo < g0i)) { w0 = vo; g0i = eo; }
            }
            double w1 = (e == g0i) ? -1.0e300 : ad; int g1i = e;
            #pragma unroll
            for (int m = 1; m < 8; m <<= 1) {
                double vo = __shfl_xor(w1, m, 64);
                int eo = __shfl_xor(g1i, m, 64);
                if (vo > w1 || (vo == w1 && eo < g1i)) { w1 = vo; g1i = eo; }
            }
            dv0 = w0; dv1 = w1; f0 = g0i; f1 = g1i;
        }

        if (e == 0) {
            float t1 = expf((float)(dv1 - dv0));
            float s = 1.f + t1;
            float g0 = 1.f / s;
            float g1 = t1 / s;
            atomicAdd(&imp_s[f0], g0);
            atomicAdd(&imp_s[f1], g1);
            if (g0 > 0.f) atomicAdd(&load_s[f0], 1);
            if (g1 > 0.f) atomicAdd(&load_s[f1], 1);
            int p0 = atomicAdd(&counts_s[f0], 1);
            int p1 = atomicAdd(&counts_s[f1], 1);
            int rl = rloc * 2;
            rec_e[rl] = f0; rec_e[rl + 1] = f1;
            rec_g[rl] = g0; rec_g[rl + 1] = g1;
            rec_p[rl] = p0; rec_p[rl + 1] = p1;
        }
    }
    __syncthreads();
    if (tid < NE) {
        base_s[tid] = atomicAdd(&gcount[tid], counts_s[tid]);
        atomicAdd(&gimp[tid], imp_s[tid]);
        atomicAdd(&gload[tid], load_s[tid]);
    }
    __syncthreads();
    if (tid < 128) {
        int ee = rec_e[tid];
        int pos = base_s[ee] + rec_p[tid];
        int rw = bx * 64 + (tid >> 1);
        idx_list[ee * BN + pos] = rw;
        gate_list[ee * BN + pos] = rec_g[tid];
    }
}

// ---------------- expert compute: R7 mapping + counted-vmcnt pipeline -------
// Wave w owns rows 16w..16w+15 (wave-private): A-fragments loaded DIRECTLY
// from global (R3-verified pattern, zero redundancy), so A never touches LDS.
// W1 double-buffered (2x32KB): cp16(kt+1) issued at tile top; before MFMA(kt)
// wait vmcnt(12) (8 cp16 + 4 x-loads of kt+1 stay IN FLIGHT across the raw
// s_barrier) -- the prefetch overlaps MFMA, unlike __syncthreads' vmcnt(0)
// drain. Stage-2 B2 chunks (2x16KB) pipelined the same way with vmcnt(4).
// H handoff is wave-private (lgkmcnt fence only, no block barrier).
// LDS: wb0 [0,32K) wb1 [32K,64K); stage2: H [0,32K), chunks [32K,48K)/[48K,64K).
__global__ __launch_bounds__(256, 2) void expert_kernel(
    const float* __restrict__ x,
    const float* __restrict__ b1, const float* __restrict__ b2,
    const float* __restrict__ Wout,
    const float* __restrict__ W1F, const float* __restrict__ W2F,
    const int* __restrict__ gcount,
    const float* __restrict__ gimp, const int* __restrict__ gload,
    const int* __restrict__ idx_list, const float* __restrict__ gate_list,
    float* __restrict__ out)
{
    __shared__ __align__(16) char smx[65536];

    int e = blockIdx.y;
    int cnt = gcount[e];
    int row0 = blockIdx.x * 64;
    // fused load-balancing loss (one thread device-wide)
    if (e == 0 && blockIdx.x == 0 && threadIdx.x == 0) {
        float mi = 0.f, ml = 0.f;
        for (int k = 0; k < NE; ++k) { mi += gimp[k]; ml += (float)gload[k]; }
        mi *= 0.125f; ml *= 0.125f;
        float vi = 0.f, vl = 0.f;
        for (int k = 0; k < NE; ++k) {
            float d = gimp[k] - mi;  vi += d * d;
            float d2 = (float)gload[k] - ml; vl += d2 * d2;
        }
        vi *= (1.f / 7.f); vl *= (1.f / 7.f);
        out[BN * 2] = (vi / (mi * mi + 1e-10f) + vl / (ml * ml + 1e-10f)) * 0.01f;
    }
    if (row0 >= cnt) return;
    int t = threadIdx.x;
    int l = t & 63, w = t >> 6;   // wave w owns rows 16w..16w+15

    // per-lane A row pointer: lane l -> row l&15 of wave's block, k-octet l>>4
    int rA = row0 + w * 16 + (l & 15);
    if (rA >= cnt) rA = cnt - 1;
    const float* pA = x + (size_t)idx_list[e * BN + rA] * IN + 8 * (l >> 4);

    // hoist b1 (keeps the stage-2 vmcnt ledger clean: no stray vmem in loops)
    float b1r[8];
    #pragma unroll
    for (int nf = 0; nf < 8; ++nf) b1r[nf] = b1[e * NH + nf * 16 + (l & 15)];

    const float* W1e = W1F + (size_t)e * 65536;
    const float* W2e = W2F + (size_t)e * 32768;

    // ---- stage-1 prologue: x(0) regs + W1(0) -> wb0 ----
    float4 rx[2][2];
    rx[0][0] = *(const float4*)(pA);
    rx[0][1] = *(const float4*)(pA + 4);
    rx[1][0] = *(const float4*)(pA + 32);
    rx[1][1] = *(const float4*)(pA + 36);
    {
        float* lb = (float*)smx;
        #pragma unroll
        for (int p = 0; p < 8; ++p)
            cp16(W1e + (p * 256 + t) * 4, lb + (p * 256 + t) * 4);
    }

    // ---- stage 1: H[64x128] = relu(X @ W1 + b1), 8 K-tiles of 64 ----
    f32x4 acc1[8] = {};
    #pragma unroll
    for (int kt = 0; kt < 8; ++kt) {
        float4 rn[2][2];
        if (kt < 7) {
            const float* pn = pA + (kt + 1) * 64;
            rn[0][0] = *(const float4*)(pn);
            rn[0][1] = *(const float4*)(pn + 4);
            rn[1][0] = *(const float4*)(pn + 32);
            rn[1][1] = *(const float4*)(pn + 36);
            const float* gb = W1e + (size_t)(kt + 1) * 8192;
            float* lb = (float*)(smx + ((kt + 1) & 1) * 32768);
            #pragma unroll
            for (int p = 0; p < 8; ++p)
                cp16(gb + (p * 256 + t) * 4, lb + (p * 256 + t) * 4);
        }
        __builtin_amdgcn_sched_barrier(0);
        // convert x(kt) -> split-bf16 A fragments (in registers)
        bf16x8 ah[2], al[2];
        #pragma unroll
        for (int ks = 0; ks < 2; ++ks) {
            float v[8] = {rx[ks][0].x, rx[ks][0].y, rx[ks][0].z, rx[ks][0].w,
                          rx[ks][1].x, rx[ks][1].y, rx[ks][1].z, rx[ks][1].w};
            #pragma unroll
            for (int i = 0; i < 8; ++i) {
                unsigned short h = f2bf(v[i]);
                ah[ks][i] = (short)h;
                al[ks][i] = (short)f2bf(v[i] - bf2f(h));
            }
        }
        // cp16(kt) landed iff outstanding <= newer ops (8 cp16 + 4 x of kt+1)
        if (kt < 7) asm volatile("s_waitcnt vmcnt(12)" ::: "memory");
        else        asm volatile("s_waitcnt vmcnt(0)" ::: "memory");
        __builtin_amdgcn_sched_barrier(0);
        __builtin_amdgcn_s_barrier();
        __builtin_amdgcn_sched_barrier(0);
        const char* wbase = smx + (kt & 1) * 32768;
        #pragma unroll
        for (int ks = 0; ks < 2; ++ks)
            #pragma unroll
            for (int nf = 0; nf < 8; ++nf) {
                int bo = ((ks * 8 + nf) * 64 + l) * 16;
                bf16x8 bh = *(const bf16x8*)(wbase + bo);
                bf16x8 bl = *(const bf16x8*)(wbase + 16384 + bo);
                acc1[nf] = __builtin_amdgcn_mfma_f32_16x16x32_bf16(ah[ks], bh, acc1[nf], 0, 0, 0);
                acc1[nf] = __builtin_amdgcn_mfma_f32_16x16x32_bf16(ah[ks], bl, acc1[nf], 0, 0, 0);
                acc1[nf] = __builtin_amdgcn_mfma_f32_16x16x32_bf16(al[ks], bh, acc1[nf], 0, 0, 0);
                acc1[nf] = __builtin_amdgcn_mfma_f32_16x16x32_bf16(al[ks], bl, acc1[nf], 0, 0, 0);
            }
        __builtin_amdgcn_sched_barrier(0);
        __builtin_amdgcn_s_barrier();   // protects wb[(kt+2)&1] overwrite
        if (kt < 7) {
            rx[0][0] = rn[0][0]; rx[0][1] = rn[0][1];
            rx[1][0] = rn[1][0]; rx[1][1] = rn[1][1];
        }
    }

    // ---- issue B2 chunk 0 (flies under the H conversion below) ----
    {
        float* lb = (float*)(smx + 32768);
        #pragma unroll
        for (int p = 0; p < 2; ++p) {
            cp16(W2e + (p * 256 + t) * 4, lb + (p * 256 + t) * 4);
            cp16(W2e + 4096 + (p * 256 + t) * 4, lb + 2048 + (p * 256 + t) * 4);
        }
    }
    // ---- relu(+b1), split, write H into wave-private LDS region ----
    {
        int rlow = 4 * (l >> 4);
        #pragma unroll
        for (int nf = 0; nf < 8; ++nf) {
            int c = nf * 16 + (l & 15);
            float b1v = b1r[nf];
            int kt2c = c >> 5;
            int g2 = (c >> 3) & 3;
            int boff = ((kt2c * 4 + w) * 64) * 16 + (c & 7) * 2;
            #pragma unroll
            for (int rg = 0; rg < 4; ++rg) {
                float v = fmaxf(acc1[nf][rg] + b1v, 0.f);
                unsigned short hh = f2bf(v);
                unsigned short hl = f2bf(v - bf2f(hh));
                int off = boff + ((rlow + rg) + 16 * g2) * 16;
                *(unsigned short*)(smx + off) = hh;
                *(unsigned short*)(smx + 16384 + off) = hl;
            }
        }
    }
    asm volatile("s_waitcnt lgkmcnt(0)" ::: "memory");  // own H writes visible
    __builtin_amdgcn_sched_barrier(0);

    // ---- stage 2: Z[64x256] = H @ W2; 8 chunks (kt2 x nh2), dbuf + vmcnt(4) --
    f32x4 acc2[16] = {};
    bf16x8 ah2 = {}, al2 = {};
    #pragma unroll
    for (int c = 0; c < 8; ++c) {
        int kt2 = c >> 1, nh2 = c & 1;
        if (c < 7) {
            int kn = c + 1;
            const float* gh = W2e + (kn >> 1) * 8192 + (kn & 1) * 2048;
            const float* gl = gh + 4096;
            float* lb = (float*)(smx + 32768 + (kn & 1) * 16384);
            #pragma unroll
            for (int p = 0; p < 2; ++p) {
                cp16(gh + (p * 256 + t) * 4, lb + (p * 256 + t) * 4);
                cp16(gl + (p * 256 + t) * 4, lb + 2048 + (p * 256 + t) * 4);
            }
        }
        __builtin_amdgcn_sched_barrier(0);
        if ((c & 1) == 0) {   // new kt2: read own-wave H A-fragments
            int ao = ((kt2 * 4 + w) * 64 + l) * 16;
            ah2 = *(const bf16x8*)(smx + ao);
            al2 = *(const bf16x8*)(smx + 16384 + ao);
        }
        if (c < 7) asm volatile("s_waitcnt vmcnt(4)" ::: "memory");
        else       asm volatile("s_waitcnt vmcnt(0)" ::: "memory");
        __builtin_amdgcn_sched_barrier(0);
        __builtin_amdgcn_s_barrier();
        __builtin_amdgcn_sched_barrier(0);
        const char* cb = smx + 32768 + (c & 1) * 16384;
        #pragma unroll
        for (int nf2 = 0; nf2 < 8; ++nf2) {
            int bo = (nf2 * 64 + l) * 16;
            bf16x8 bh = *(const bf16x8*)(cb + bo);
            bf16x8 bl = *(const bf16x8*)(cb + 8192 + bo);
            int nf = nh2 * 8 + nf2;
            acc2[nf] = __builtin_amdgcn_mfma_f32_16x16x32_bf16(ah2, bh, acc2[nf], 0, 0, 0);
            acc2[nf] = __builtin_amdgcn_mfma_f32_16x16x32_bf16(ah2, bl, acc2[nf], 0, 0, 0);
            acc2[nf] = __builtin_amdgcn_mfma_f32_16x16x32_bf16(al2, bh, acc2[nf], 0, 0, 0);
            acc2[nf] = __builtin_amdgcn_mfma_f32_16x16x32_bf16(al2, bl, acc2[nf], 0, 0, 0);
        }
        __builtin_amdgcn_sched_barrier(0);
        __builtin_amdgcn_s_barrier();
    }

    // ---- epilogue: single-wave softmax over 256 cols, fused @Wout ----
    #pragma unroll
    for (int nf = 0; nf < 16; ++nf) {
        float b2v = b2[e * MO + nf * 16 + (l & 15)];
        #pragma unroll
        for (int rg = 0; rg < 4; ++rg) acc2[nf][rg] += b2v;
    }
    #pragma unroll
    for (int rg = 0; rg < 4; ++rg) {
        float m = -1e30f;
        #pragma unroll
        for (int nf = 0; nf < 16; ++nf) m = fmaxf(m, acc2[nf][rg]);
        m = fmaxf(m, __shfl_xor(m, 1, 64));
        m = fmaxf(m, __shfl_xor(m, 2, 64));
        m = fmaxf(m, __shfl_xor(m, 4, 64));
        m = fmaxf(m, __shfl_xor(m, 8, 64));
        float s = 0.f, o0 = 0.f, o1 = 0.f;
        #pragma unroll
        for (int nf = 0; nf < 16; ++nf) {
            float tt = __expf(acc2[nf][rg] - m);
            s += tt;
            float2 wv = *(const float2*)&Wout[2 * (nf * 16 + (l & 15))];
            o0 = fmaf(tt, wv.x, o0);
            o1 = fmaf(tt, wv.y, o1);
        }
        s += __shfl_xor(s, 1, 64); s += __shfl_xor(s, 2, 64);
        s += __shfl_xor(s, 4, 64); s += __shfl_xor(s, 8, 64);
        o0 += __shfl_xor(o0, 1, 64); o0 += __shfl_xor(o0, 2, 64);
        o0 += __shfl_xor(o0, 4, 64); o0 += __shfl_xor(o0, 8, 64);
        o1 += __shfl_xor(o1, 1, 64); o1 += __shfl_xor(o1, 2, 64);
        o1 += __shfl_xor(o1, 4, 64); o1 += __shfl_xor(o1, 8, 64);
        if ((l & 15) == 0) {
            int gi = row0 + w * 16 + 4 * (l >> 4) + rg;
            if (gi < cnt) {
                float g = gate_list[e * BN + gi];
                int brow = idx_list[e * BN + gi];
                float inv = 1.f / s;
                atomicAdd(&out[brow * 2 + 0], g * o0 * inv);
                atomicAdd(&out[brow * 2 + 1], g * o1 * inv);
            }
        }
    }
}

extern "C" void kernel_launch(void* const* d_in, const int* in_sizes, int n_in,
                              void* d_out, int out_size, void* d_ws, size_t ws_size,
                              hipStream_t stream) {
    const float* x    = (const float*)d_in[0];
    // d_in[1] = cat_prop, unused by the reference
    const float* wg   = (const float*)d_in[2];
    const float* W1   = (const float*)d_in[3];
    const float* b1   = (const float*)d_in[4];
    const float* W2   = (const float*)d_in[5];
    const float* b2   = (const float*)d_in[6];
    const float* Wout = (const float*)d_in[7];
    const float* bout = (const float*)d_in[8];
    float* out = (float*)d_out;

    char* ws = (char*)d_ws;
    int*   gcount    = (int*)(ws + 0);
    int*   gload     = (int*)(ws + 32);
    float* gimp      = (float*)(ws + 64);
    int*   idx_list  = (int*)(ws + 128);
    float* gate_list = (float*)(ws + 128 + sizeof(int) * NE * BN);
    float* W1F       = (float*)(ws + 128 + 8 * NE * BN);                // 2 MB
    float* W2F       = (float*)(ws + 128 + 8 * NE * BN + 64 * 32768);  // 1 MB

    hipMemsetAsync(ws, 0, 128, stream);
    gatep_kernel<<<608, 256, 0, stream>>>(x, wg, W1, W2, W1F, W2F,
                                          gcount, gload, gimp,
                                          idx_list, gate_list, out, bout);
    dim3 eg(BN / 64, NE);
    expert_kernel<<<eg, 256, 0, stream>>>(x, b1, b2, Wout, W1F, W2F,
                                          gcount, gimp, gload,
                                          idx_list, gate_list, out);
}

// Round 11
// 201.728 us; speedup vs baseline: 1.0581x; 1.0581x over previous
//
#include <hip/hip_runtime.h>

#define BN 32768
#define IN 512
#define NE 8
#define NH 128
#define MO 256

typedef const __attribute__((address_space(1))) unsigned int gu32;
typedef __attribute__((address_space(3))) unsigned int lu32;
typedef __attribute__((ext_vector_type(8))) short bf16x8;
typedef __attribute__((ext_vector_type(4))) float f32x4;

// async global->LDS, 16B per lane. LDS dest = wave-uniform base + lane*16.
__device__ __forceinline__ void cp16(const float* g, float* l) {
    __builtin_amdgcn_global_load_lds((gu32*)g, (lu32*)l, 16, 0, 0);
}

// f32 -> bf16 bits, round-to-nearest-even
__device__ __forceinline__ unsigned short f2bf(float f) {
    unsigned int u = __float_as_uint(f);
    u = (u + 0x7fffu + ((u >> 16) & 1u)) >> 16;
    return (unsigned short)u;
}
__device__ __forceinline__ float bf2f(unsigned short h) {
    return __uint_as_float((unsigned int)h << 16);
}

// ---------------- fused gate (blocks 0..511) + weight prep (512..607) -------
// Both paths byte-identical to R7 (verified passing, 209.0us total).
__global__ __launch_bounds__(256) void gatep_kernel(
    const float* __restrict__ x, const float* __restrict__ wg,
    const float* __restrict__ W1, const float* __restrict__ W2,
    float* __restrict__ W1F, float* __restrict__ W2F,
    int* __restrict__ gcount, int* __restrict__ gload, float* __restrict__ gimp,
    int* __restrict__ idx_list, float* __restrict__ gate_list,
    float* __restrict__ out, const float* __restrict__ bout)
{
    __shared__ __align__(16) char wb[32768];
    __shared__ int counts_s[NE];
    __shared__ int load_s[NE];
    __shared__ float imp_s[NE];
    __shared__ int base_s[NE];
    __shared__ int rec_e[128];
    __shared__ int rec_p[128];
    __shared__ float rec_g[128];

    int tid = threadIdx.x;
    int bx = blockIdx.x;

    if (bx >= 512) {    // ---------- prep path ----------
        char* pb = wb;
        int t = tid, b = bx - 512;
        if (b < 64) {                       // W1: e = b>>3, ktile(64 k) = b&7
            int e = b >> 3, kt = b & 7;
            const float* src = W1 + ((size_t)e * IN + kt * 64) * NH;
            #pragma unroll
            for (int p = 0; p < 8; ++p) {
                int li = p * 256 + t;
                float4 q = *(const float4*)(src + li * 4);
                int kl = li >> 5, n0 = (li & 31) * 4;
                int ks = kl >> 5, g = (kl >> 3) & 3, kb = (kl & 7) * 2;
                float vv[4] = {q.x, q.y, q.z, q.w};
                #pragma unroll
                for (int j = 0; j < 4; ++j) {
                    int n = n0 + j;
                    int off = (((ks * 8 + (n >> 4)) * 64) + (n & 15) + 16 * g) * 16 + kb;
                    unsigned short hh = f2bf(vv[j]);
                    unsigned short hl = f2bf(vv[j] - bf2f(hh));
                    *(unsigned short*)(pb + off) = hh;
                    *(unsigned short*)(pb + 16384 + off) = hl;
                }
            }
            __syncthreads();
            float* dst = W1F + (size_t)b * 8192;
            #pragma unroll
            for (int p = 0; p < 8; ++p) {
                int li = p * 256 + t;
                *(int4*)(dst + li * 4) = *(const int4*)(pb + li * 16);
            }
        } else {                            // W2: e = bi>>2, ktile(32 k) = bi&3
            int bi = b - 64;
            int e = bi >> 2, kt = bi & 3;
            const float* src = W2 + ((size_t)e * NH + kt * 32) * MO;
            #pragma unroll
            for (int p = 0; p < 8; ++p) {
                int li = p * 256 + t;
                float4 q = *(const float4*)(src + li * 4);
                int kl = li >> 6, n0 = (li & 63) * 4;
                int g = kl >> 3, kb = (kl & 7) * 2;
                float vv[4] = {q.x, q.y, q.z, q.w};
                #pragma unroll
                for (int j = 0; j < 4; ++j) {
                    int n = n0 + j;
                    int off = ((n >> 4) * 64 + (n & 15) + 16 * g) * 16 + kb;
                    unsigned short hh = f2bf(vv[j]);
                    unsigned short hl = f2bf(vv[j] - bf2f(hh));
                    *(unsigned short*)(pb + off) = hh;
                    *(unsigned short*)(pb + 16384 + off) = hl;
                }
            }
            __syncthreads();
            float* dst = W2F + (size_t)bi * 8192;
            #pragma unroll
            for (int p = 0; p < 8; ++p) {
                int li = p * 256 + t;
                *(int4*)(dst + li * 4) = *(const int4*)(pb + li * 16);
            }
        }
        return;
    }

    // ---------- gate path ----------
    if (tid < NE) { counts_s[tid] = 0; load_s[tid] = 0; imp_s[tid] = 0.f; }
    if (tid < 128) {  // fused init: out[row, j] = bout[j]
        int row = bx * 64 + (tid >> 1);
        out[row * 2 + (tid & 1)] = bout[tid & 1];
    }
    for (int idx = tid; idx < 1024; idx += 256) {
        int ks = idx >> 6, ls = idx & 63;
        int col = ls & 15;
        int kb = 32 * ks + 8 * (ls >> 4);
        unsigned int ph[4], pl[4];
        #pragma unroll
        for (int j = 0; j < 4; ++j) {
            float v0 = (col < 8) ? wg[(kb + 2 * j) * NE + col] : 0.f;
            float v1 = (col < 8) ? wg[(kb + 2 * j + 1) * NE + col] : 0.f;
            unsigned short h0 = f2bf(v0), h1 = f2bf(v1);
            unsigned short l0 = f2bf(v0 - bf2f(h0)), l1 = f2bf(v1 - bf2f(h1));
            ph[j] = (unsigned int)h0 | ((unsigned int)h1 << 16);
            pl[j] = (unsigned int)l0 | ((unsigned int)l1 << 16);
        }
        *(int4*)(wb + ks * 1024 + ls * 16) = make_int4(ph[0], ph[1], ph[2], ph[3]);
        *(int4*)(wb + 16384 + ks * 1024 + ls * 16) = make_int4(pl[0], pl[1], pl[2], pl[3]);
    }
    __syncthreads();

    int w = tid >> 6, l = tid & 63;
    int e = l & 15;
    int rowA = bx * 64 + w * 16 + e;
    const float* px = x + (size_t)rowA * IN + 8 * (l >> 4);

    f32x4 acc = {};
    #pragma unroll
    for (int ks = 0; ks < 16; ++ks) {
        float4 qa = *(const float4*)(px + 32 * ks);
        float4 qb = *(const float4*)(px + 32 * ks + 4);
        float v[8] = {qa.x, qa.y, qa.z, qa.w, qb.x, qb.y, qb.z, qb.w};
        bf16x8 ah, al;
        #pragma unroll
        for (int i = 0; i < 8; ++i) {
            unsigned short h = f2bf(v[i]);
            ah[i] = (short)h;
            al[i] = (short)f2bf(v[i] - bf2f(h));
        }
        bf16x8 bh = *(const bf16x8*)(wb + ks * 1024 + l * 16);
        bf16x8 bl = *(const bf16x8*)(wb + 16384 + ks * 1024 + l * 16);
        acc = __builtin_amdgcn_mfma_f32_16x16x32_bf16(ah, bh, acc, 0, 0, 0);
        acc = __builtin_amdgcn_mfma_f32_16x16x32_bf16(ah, bl, acc, 0, 0, 0);
        acc = __builtin_amdgcn_mfma_f32_16x16x32_bf16(al, bh, acc, 0, 0, 0);
    }

    #pragma unroll
    for (int reg = 0; reg < 4; ++reg) {
        int rloc = w * 16 + 4 * (l >> 4) + reg;
        int row = bx * 64 + rloc;
        float lv = (e < 8) ? acc[reg] : -1e30f;

        float v0 = lv; int e0 = e;
        #pragma unroll
        for (int m = 1; m < 8; m <<= 1) {
            float vo = __shfl_xor(v0, m, 64);
            int eo = __shfl_xor(e0, m, 64);
            if (vo > v0 || (vo == v0 && eo < e0)) { v0 = vo; e0 = eo; }
        }
        float v1 = (e == e0 || e >= 8) ? -1e30f : lv; int e1 = e;
        #pragma unroll
        for (int m = 1; m < 8; m <<= 1) {
            float vo = __shfl_xor(v1, m, 64);
            int eo = __shfl_xor(e1, m, 64);
            if (vo > v1 || (vo == v1 && eo < e1)) { v1 = vo; e1 = eo; }
        }
        float v2 = (e == e0 || e == e1 || e >= 8) ? -1e30f : lv;
        #pragma unroll
        for (int m = 1; m < 8; m <<= 1) v2 = fmaxf(v2, __shfl_xor(v2, m, 64));

        double dv0 = v0, dv1 = v1;
        int f0 = e0, f1 = e1;
        if (e < 8 && v1 - v2 < 2e-4f) {   // rare exact recompute (group-uniform)
            const float* xr = x + (size_t)row * IN;
            double d0 = 0, d1 = 0, d2 = 0, d3 = 0;
            for (int k = 0; k < IN; k += 4) {
                float4 xv = *(const float4*)(xr + k);
                d0 = fma((double)xv.x, (double)wg[(k    ) * NE + e], d0);
                d1 = fma((double)xv.y, (double)wg[(k + 1) * NE + e], d1);
                d2 = fma((double)xv.z, (double)wg[(k + 2) * NE + e], d2);
                d3 = fma((double)xv.w, (double)wg[(k + 3) * NE + e], d3);
            }
            double ad = (d0 + d1) + (d2 + d3);
            double w0 = ad; int g0i = e;
            #pragma unroll
            for (int m = 1; m < 8; m <<= 1) {
                double vo = __shfl_xor(w0, m, 64);
                int eo = __shfl_xor(g0i, m, 64);
                if (vo > w0 || (vo == w0 && eo < g0i)) { w0 = vo; g0i = eo; }
            }
            double w1 = (e == g0i) ? -1.0e300 : ad; int g1i = e;
            #pragma unroll
            for (int m = 1; m < 8; m <<= 1) {
                double vo = __shfl_xor(w1, m, 64);
                int eo = __shfl_xor(g1i, m, 64);
                if (vo > w1 || (vo == w1 && eo < g1i)) { w1 = vo; g1i = eo; }
            }
            dv0 = w0; dv1 = w1; f0 = g0i; f1 = g1i;
        }

        if (e == 0) {
            float t1 = expf((float)(dv1 - dv0));
            float s = 1.f + t1;
            float g0 = 1.f / s;
            float g1 = t1 / s;
            atomicAdd(&imp_s[f0], g0);
            atomicAdd(&imp_s[f1], g1);
            if (g0 > 0.f) atomicAdd(&load_s[f0], 1);
            if (g1 > 0.f) atomicAdd(&load_s[f1], 1);
            int p0 = atomicAdd(&counts_s[f0], 1);
            int p1 = atomicAdd(&counts_s[f1], 1);
            int rl = rloc * 2;
            rec_e[rl] = f0; rec_e[rl + 1] = f1;
            rec_g[rl] = g0; rec_g[rl + 1] = g1;
            rec_p[rl] = p0; rec_p[rl + 1] = p1;
        }
    }
    __syncthreads();
    if (tid < NE) {
        base_s[tid] = atomicAdd(&gcount[tid], counts_s[tid]);
        atomicAdd(&gimp[tid], imp_s[tid]);
        atomicAdd(&gload[tid], load_s[tid]);
    }
    __syncthreads();
    if (tid < 128) {
        int ee = rec_e[tid];
        int pos = base_s[ee] + rec_p[tid];
        int rw = bx * 64 + (tid >> 1);
        idx_list[ee * BN + pos] = rw;
        gate_list[ee * BN + pos] = rec_g[tid];
    }
}

// ---------------- expert compute: R7 structure, 3-term split ----------------
// Byte-identical to the measured-best R7 (82.6us) EXCEPT the lo*lo MFMA term
// is dropped in both stages (-25% MFMA work). Error audit: bf16 pair already
// carries ~2^-17 relative representation error (the 3.05e-5 absmax); the ll
// term is <=2^-18 -> absmax rises ~1.5x at most. Gate is already 3-term.
__global__ __launch_bounds__(256, 3) void expert_kernel(
    const float* __restrict__ x,
    const float* __restrict__ b1, const float* __restrict__ b2,
    const float* __restrict__ Wout,
    const float* __restrict__ W1F, const float* __restrict__ W2F,
    const int* __restrict__ gcount,
    const float* __restrict__ gimp, const int* __restrict__ gload,
    const int* __restrict__ idx_list, const float* __restrict__ gate_list,
    float* __restrict__ out)
{
    __shared__ __align__(16) char smx[49152];
    __shared__ float woutS[512];

    int e = blockIdx.y;
    int cnt = gcount[e];
    int row0 = blockIdx.x * 64;
    // fused load-balancing loss (one thread device-wide)
    if (e == 0 && blockIdx.x == 0 && threadIdx.x == 0) {
        float mi = 0.f, ml = 0.f;
        for (int k = 0; k < NE; ++k) { mi += gimp[k]; ml += (float)gload[k]; }
        mi *= 0.125f; ml *= 0.125f;
        float vi = 0.f, vl = 0.f;
        for (int k = 0; k < NE; ++k) {
            float d = gimp[k] - mi;  vi += d * d;
            float d2 = (float)gload[k] - ml; vl += d2 * d2;
        }
        vi *= (1.f / 7.f); vl *= (1.f / 7.f);
        out[BN * 2] = (vi / (mi * mi + 1e-10f) + vl / (ml * ml + 1e-10f)) * 0.01f;
    }
    if (row0 >= cnt) return;
    int t = threadIdx.x;
    int l = t & 63, w = t >> 6;   // wave w owns M-frag w (rows 16w..16w+15)

    woutS[t] = Wout[t];
    woutS[256 + t] = Wout[256 + t];

    // staging decomposition: thread -> (mfrag, row-low, k-octet)
    int s_r  = t & 15;
    int s_g  = (t >> 4) & 3;
    int s_mf = t >> 6;
    int rloc_s = s_mf * 16 + s_r;
    int sgi = row0 + rloc_s; if (sgi >= cnt) sgi = cnt - 1;
    const float* xrow = x + (size_t)idx_list[e * BN + sgi] * IN;

    const float* W1e = W1F + (size_t)e * 65536;
    const float* W2e = W2F + (size_t)e * 32768;

    // ---- stage 1: H[64x128] = relu(X @ W1 + b1), 8 K-tiles of 64 ----
    // A: hi 0..8K, lo 8K..16K; W1 blob: 16K..48K (hi 16K, lo 16K)
    f32x4 acc1[8] = {};
    for (int kt = 0; kt < 8; ++kt) {
        {
            const float* gb = W1e + (size_t)kt * 8192;
            float* lb = (float*)(smx + 16384);
            #pragma unroll
            for (int p = 0; p < 8; ++p)
                cp16(gb + (p * 256 + t) * 4, lb + (p * 256 + t) * 4);
        }
        #pragma unroll
        for (int ks = 0; ks < 2; ++ks) {
            int k = kt * 64 + ks * 32 + s_g * 8;
            float4 qa = *(const float4*)(xrow + k);
            float4 qb = *(const float4*)(xrow + k + 4);
            float vv[8] = {qa.x, qa.y, qa.z, qa.w, qb.x, qb.y, qb.z, qb.w};
            unsigned int dh[4], dl[4];
            #pragma unroll
            for (int j = 0; j < 4; ++j) {
                unsigned short h0 = f2bf(vv[2 * j]);
                unsigned short h1 = f2bf(vv[2 * j + 1]);
                unsigned short l0 = f2bf(vv[2 * j] - bf2f(h0));
                unsigned short l1 = f2bf(vv[2 * j + 1] - bf2f(h1));
                dh[j] = (unsigned int)h0 | ((unsigned int)h1 << 16);
                dl[j] = (unsigned int)l0 | ((unsigned int)l1 << 16);
            }
            int slot = ((ks * 4 + s_mf) * 64 + (s_r + 16 * s_g)) * 16;
            *(int4*)(smx + slot) = make_int4(dh[0], dh[1], dh[2], dh[3]);
            *(int4*)(smx + 8192 + slot) = make_int4(dl[0], dl[1], dl[2], dl[3]);
        }
        __syncthreads();
        #pragma unroll
        for (int ks = 0; ks < 2; ++ks) {
            int ao = ((ks * 4 + w) * 64 + l) * 16;
            bf16x8 ah = *(const bf16x8*)(smx + ao);
            bf16x8 al = *(const bf16x8*)(smx + 8192 + ao);
            #pragma unroll
            for (int nf = 0; nf < 8; ++nf) {
                int bo = ((ks * 8 + nf) * 64 + l) * 16;
                bf16x8 bh = *(const bf16x8*)(smx + 16384 + bo);
                bf16x8 bl = *(const bf16x8*)(smx + 32768 + bo);
                acc1[nf] = __builtin_amdgcn_mfma_f32_16x16x32_bf16(ah, bh, acc1[nf], 0, 0, 0);
                acc1[nf] = __builtin_amdgcn_mfma_f32_16x16x32_bf16(ah, bl, acc1[nf], 0, 0, 0);
                acc1[nf] = __builtin_amdgcn_mfma_f32_16x16x32_bf16(al, bh, acc1[nf], 0, 0, 0);
                // ll term dropped (3-term split)
            }
        }
        __syncthreads();
    }

    // ---- relu(+b1), split, write H as stage-2 A-fragments (hi 0..16K, lo 16K..32K) ----
    {
        int rlow = 4 * (l >> 4);
        #pragma unroll
        for (int nf = 0; nf < 8; ++nf) {
            int c = nf * 16 + (l & 15);
            float b1v = b1[e * NH + c];
            int kt2c = c >> 5;
            int g2 = (c >> 3) & 3;
            int boff = ((kt2c * 4 + w) * 64) * 16 + (c & 7) * 2;
            #pragma unroll
            for (int rg = 0; rg < 4; ++rg) {
                float v = fmaxf(acc1[nf][rg] + b1v, 0.f);
                unsigned short hh = f2bf(v);
                unsigned short hl = f2bf(v - bf2f(hh));
                int off = boff + ((rlow + rg) + 16 * g2) * 16;
                *(unsigned short*)(smx + off) = hh;
                *(unsigned short*)(smx + 16384 + off) = hl;
            }
        }
    }
    __syncthreads();

    // ---- stage 2: Z[64x256] = H @ W2, 4 K-tiles of 32, B2 in 16KB N-halves ----
    f32x4 acc2[16] = {};
    for (int kt2 = 0; kt2 < 4; ++kt2) {
        int ao = ((kt2 * 4 + w) * 64 + l) * 16;
        bf16x8 ah2 = *(const bf16x8*)(smx + ao);
        bf16x8 al2 = *(const bf16x8*)(smx + 16384 + ao);
        #pragma unroll
        for (int nh2 = 0; nh2 < 2; ++nh2) {
            {   // stage 8KB hi + 8KB lo chunk into 32K..48K
                const float* gh = W2e + kt2 * 8192 + nh2 * 2048;
                const float* gl = W2e + kt2 * 8192 + 4096 + nh2 * 2048;
                float* lb = (float*)(smx + 32768);
                #pragma unroll
                for (int p = 0; p < 2; ++p) {
                    cp16(gh + (p * 256 + t) * 4, lb + (p * 256 + t) * 4);
                    cp16(gl + (p * 256 + t) * 4, lb + 2048 + (p * 256 + t) * 4);
                }
            }
            __syncthreads();
            #pragma unroll
            for (int nf2 = 0; nf2 < 8; ++nf2) {
                int bo = (nf2 * 64 + l) * 16;
                bf16x8 bh = *(const bf16x8*)(smx + 32768 + bo);
                bf16x8 bl = *(const bf16x8*)(smx + 40960 + bo);
                int nf = nh2 * 8 + nf2;
                acc2[nf] = __builtin_amdgcn_mfma_f32_16x16x32_bf16(ah2, bh, acc2[nf], 0, 0, 0);
                acc2[nf] = __builtin_amdgcn_mfma_f32_16x16x32_bf16(ah2, bl, acc2[nf], 0, 0, 0);
                acc2[nf] = __builtin_amdgcn_mfma_f32_16x16x32_bf16(al2, bh, acc2[nf], 0, 0, 0);
                // ll term dropped (3-term split)
            }
            __syncthreads();
        }
    }

    // ---- epilogue: single-wave softmax over 256 cols, fused @Wout ----
    #pragma unroll
    for (int nf = 0; nf < 16; ++nf) {
        float b2v = b2[e * MO + nf * 16 + (l & 15)];
        #pragma unroll
        for (int rg = 0; rg < 4; ++rg) acc2[nf][rg] += b2v;
    }
    #pragma unroll
    for (int rg = 0; rg < 4; ++rg) {
        float m = -1e30f;
        #pragma unroll
        for (int nf = 0; nf < 16; ++nf) m = fmaxf(m, acc2[nf][rg]);
        m = fmaxf(m, __shfl_xor(m, 1, 64));
        m = fmaxf(m, __shfl_xor(m, 2, 64));
        m = fmaxf(m, __shfl_xor(m, 4, 64));
        m = fmaxf(m, __shfl_xor(m, 8, 64));
        float s = 0.f, o0 = 0.f, o1 = 0.f;
        #pragma unroll
        for (int nf = 0; nf < 16; ++nf) {
            float tt = __expf(acc2[nf][rg] - m);
            s += tt;
            float2 wv = *(const float2*)&woutS[2 * (nf * 16 + (l & 15))];
            o0 = fmaf(tt, wv.x, o0);
            o1 = fmaf(tt, wv.y, o1);
        }
        s += __shfl_xor(s, 1, 64); s += __shfl_xor(s, 2, 64);
        s += __shfl_xor(s, 4, 64); s += __shfl_xor(s, 8, 64);
        o0 += __shfl_xor(o0, 1, 64); o0 += __shfl_xor(o0, 2, 64);
        o0 += __shfl_xor(o0, 4, 64); o0 += __shfl_xor(o0, 8, 64);
        o1 += __shfl_xor(o1, 1, 64); o1 += __shfl_xor(o1, 2, 64);
        o1 += __shfl_xor(o1, 4, 64); o1 += __shfl_xor(o1, 8, 64);
        if ((l & 15) == 0) {
            int gi = row0 + w * 16 + 4 * (l >> 4) + rg;
            if (gi < cnt) {
                float g = gate_list[e * BN + gi];
                int brow = idx_list[e * BN + gi];
                float inv = 1.f / s;
                atomicAdd(&out[brow * 2 + 0], g * o0 * inv);
                atomicAdd(&out[brow * 2 + 1], g * o1 * inv);
            }
        }
    }
}

extern "C" void kernel_launch(void* const* d_in, const int* in_sizes, int n_in,
                              void* d_out, int out_size, void* d_ws, size_t ws_size,
                              hipStream_t stream) {
    const float* x    = (const float*)d_in[0];
    // d_in[1] = cat_prop, unused by the reference
    const float* wg   = (const float*)d_in[2];
    const float* W1   = (const float*)d_in[3];
    const float* b1   = (const float*)d_in[4];
    const float* W2   = (const float*)d_in[5];
    const float* b2   = (const float*)d_in[6];
    const float* Wout = (const float*)d_in[7];
    const float* bout = (const float*)d_in[8];
    float* out = (float*)d_out;

    char* ws = (char*)d_ws;
    int*   gcount    = (int*)(ws + 0);
    int*   gload     = (int*)(ws + 32);
    float* gimp      = (float*)(ws + 64);
    int*   idx_list  = (int*)(ws + 128);
    float* gate_list = (float*)(ws + 128 + sizeof(int) * NE * BN);
    float* W1F       = (float*)(ws + 128 + 8 * NE * BN);                // 2 MB
    float* W2F       = (float*)(ws + 128 + 8 * NE * BN + 64 * 32768);  // 1 MB

    hipMemsetAsync(ws, 0, 128, stream);
    gatep_kernel<<<608, 256, 0, stream>>>(x, wg, W1, W2, W1F, W2F,
                                          gcount, gload, gimp,
                                          idx_list, gate_list, out, bout);
    dim3 eg(BN / 64, NE);
    expert_kernel<<<eg, 256, 0, stream>>>(x, b1, b2, Wout, W1F, W2F,
                                          gcount, gimp, gload,
                                          idx_list, gate_list, out);
}